// Round 2
// baseline (155.088 us; speedup 1.0000x reference)
//
#include <hip/hip_runtime.h>

#define B_ 128
#define O_ 1024
#define I_ 1024
#define NCHUNK 64
#define CI (I_ / NCHUNK)     // 16 i-values per wave
#define WPB 4                // waves per block
#define TT_BYTES ((size_t)O_ * I_ * sizeof(float))

#define LOG2E_F  1.4426950408889634f
#define LN2_F    0.6931471805599453f
#define LN2SQ_F  0.4804530139182014f          // ln2^2
#define EPSC_F   (1e-7f * LN2SQ_F)            // eps * ln2^2

typedef float v2f __attribute__((ext_vector_type(2)));

__device__ __forceinline__ float fast_rsq(float x)  { return __builtin_amdgcn_rsqf(x); }
__device__ __forceinline__ float fast_exp2(float x) { return __builtin_amdgcn_exp2f(x); }
__device__ __forceinline__ float fast_rcp(float x)  { return __builtin_amdgcn_rcpf(x); }

__device__ __forceinline__ float readlane_f(float x, int l) {
    return __builtin_bit_cast(float,
        __builtin_amdgcn_readlane(__builtin_bit_cast(int, x), l));
}

// DPP add step (ctrl must be an immediate -> template param);
// bound_ctrl=true: invalid sources read 0.
template <int CTRL>
__device__ __forceinline__ float dpp_add(float v) {
    int x = __builtin_amdgcn_update_dpp(0, __builtin_bit_cast(int, v),
                                        CTRL, 0xf, 0xf, true);
    return v + __builtin_bit_cast(float, x);
}
// 64-lane sum; total lands in lane 63, returned as SGPR-uniform float.
__device__ __forceinline__ float wave_sum_uniform(float v) {
    v = dpp_add<0xB1>(v);   // quad_perm [1,0,3,2] : pair sums
    v = dpp_add<0x4E>(v);   // quad_perm [2,3,0,1] : quad sums
    v = dpp_add<0x141>(v);  // row_half_mirror     : octet sums
    v = dpp_add<0x140>(v);  // row_mirror          : row-of-16 sums
    v = dpp_add<0x142>(v);  // row_bcast15         : rows 1..3 += prev row
    v = dpp_add<0x143>(v);  // row_bcast31         : rows 2,3 += rows 0+1
    return __builtin_bit_cast(float,
        __builtin_amdgcn_readlane(__builtin_bit_cast(int, v), 63));
}

// ---------------------------------------------------------------------------
// Fused kernel 1: Tt2[i*O+o] = T[o,i]^2 (transposed+squared), plus
//  - per-column(i) min via LDS-pre-reduced global atomicMin on uint bits
//    (valid: r2 >= 0 so float bits are monotone as unsigned),
//  - zeroing of d_out (grid 1024 blocks x 128 elems = 131072 = B*O).
// ---------------------------------------------------------------------------
__global__ __launch_bounds__(256) void build_T2_kernel(
    const float* __restrict__ ix, const float* __restrict__ iy,
    const float* __restrict__ ox, const float* __restrict__ oy,
    const float* __restrict__ la, const float* __restrict__ lm,
    float* __restrict__ Tt2, unsigned* __restrict__ minbits,
    float* __restrict__ out_zero)
{
    __shared__ float tile[32][33];
    __shared__ unsigned mloc[32];
    const int i0 = blockIdx.x * 32;
    const int o0 = blockIdx.y * 32;
    const int tx = threadIdx.x;      // 0..31
    const int ty = threadIdx.y;      // 0..7
    const int t  = ty * 32 + tx;     // 0..255

    if (t < 32) mloc[t] = 0xFFFFFFFFu;

    // fold the d_out zeroing in (saves a memset dispatch)
    const int bid = blockIdx.y * gridDim.x + blockIdx.x;   // 0..1023
    if (t < 128) out_zero[bid * 128 + t] = 0.0f;

#pragma unroll
    for (int r = 0; r < 32; r += 8) {
        const int o = o0 + ty + r;
        const int i = i0 + tx;
        const int idx = o * I_ + i;
        const float tt = fmaf(ix[idx] * fast_rcp(iy[idx]) + la[idx],
                              1.0f + lm[idx],
                              -(ox[idx] * fast_rcp(oy[idx])));
        tile[ty + r][tx] = tt * tt;
    }
    __syncthreads();
#pragma unroll
    for (int r = 0; r < 32; r += 8) {
        const int i = i0 + ty + r;
        const int o = o0 + tx;
        Tt2[i * O_ + o] = tile[tx][ty + r];
    }
    // per-i min over this block's 32 o's: thread t covers i_local=t&31,
    // o_locals = (t>>5)*4 .. +3
    const int il = t & 31;
    const int g  = t >> 5;
    float mn = fminf(fminf(tile[4 * g + 0][il], tile[4 * g + 1][il]),
                     fminf(tile[4 * g + 2][il], tile[4 * g + 3][il]));
    atomicMin(&mloc[il], __builtin_bit_cast(unsigned, mn));
    __syncthreads();
    if (t < 32) atomicMin(&minbits[i0 + t], mloc[t]);
}

// ---------------------------------------------------------------------------
// Kernel 2: wave owns chunk of 16 i's; lane owns 16 o's.
//  - __launch_bounds__(256, 8): cap VGPR at 64 -> 8 waves/SIMD (was 68 -> 7).
//  - Single-buffered row regs; the fully-unrolled body is one BB, so the
//    machine scheduler hoists next-row loads to whatever depth the 64-reg
//    budget allows (explicit ping-pong pinned 32 VGPRs and proved neutral).
//  - Prologue lane-parallelized: lane j derives per-i values for i=j
//    (3 trans total instead of 48 wave-uniform trans), then readlane -> SGPR.
// ---------------------------------------------------------------------------
__global__ __launch_bounds__(256, 8) void aeg_main_kernel(
    const float* __restrict__ data,   // (B, I)
    const float* __restrict__ Tt2,    // (I, O) transposed T^2
    const float* __restrict__ minr2,  // (I) float bits (from atomicMin)
    float* __restrict__ out)          // (B, O), zeroed by build_T2
{
    __shared__ float red[WPB][O_];    // 16 KB

    const int w    = threadIdx.x >> 6;
    const int lane = threadIdx.x & 63;
    const int chunk = blockIdx.x * WPB + w;
    const int b     = blockIdx.y;

    const float4* rowbase = (const float4*)(Tt2 + (size_t)chunk * CI * O_);

    // ---- prologue: lane j computes per-i derivations for i = chunk*CI + j ----
    const int li = lane & 15;                       // lanes 16..63 duplicate
    const float dv_l = data[b * I_ + chunk * CI + li];
    const float mr_l = minr2[chunk * CI + li];
    const float sig_l = fast_rcp(1.0f + fast_exp2(-dv_l * LOG2E_F));
    const float sc_l  = sig_l * LN2_F;
    const float s2_l  = sc_l * sc_l;
    const float m2_l  = fast_rsq(fmaf(mr_l, s2_l, EPSC_F)); // exact max (log2 units)

    float sdv[CI], ss2[CI], sm2[CI];
#pragma unroll
    for (int j = 0; j < CI; ++j) {
        sdv[j] = readlane_f(dv_l, j);
        ss2[j] = readlane_f(s2_l, j);
        sm2[j] = readlane_f(m2_l, j);
    }

    v2f acc2[8];
#pragma unroll
    for (int j = 0; j < 8; ++j) acc2[j] = (v2f)0.0f;

#pragma unroll
    for (int ii = 0; ii < CI; ++ii) {
        const float4* r4 = rowbase + (size_t)ii * (O_ / 4);
        float4 rr[4];
#pragma unroll
        for (int k = 0; k < 4; ++k) rr[k] = r4[lane + 64 * k];

        const v2f s2v = {ss2[ii], ss2[ii]};
        const v2f m2v = {sm2[ii], sm2[ii]};
        const v2f epv = {EPSC_F, EPSC_F};

        v2f e2[8];
        v2f zv0 = (v2f)0.0f, zv1 = (v2f)0.0f;
#pragma unroll
        for (int k = 0; k < 4; ++k) {
            const v2f a = {rr[k].x, rr[k].y};
            const v2f c = {rr[k].z, rr[k].w};
            const v2f q0 = a * s2v + epv;
            const v2f q1 = c * s2v + epv;
            v2f t0, t1;
            t0.x = fast_rsq(q0.x); t0.y = fast_rsq(q0.y);
            t1.x = fast_rsq(q1.x); t1.y = fast_rsq(q1.y);
            t0 -= m2v;
            t1 -= m2v;
            v2f ev0, ev1;
            ev0.x = fast_exp2(t0.x); ev0.y = fast_exp2(t0.y);
            ev1.x = fast_exp2(t1.x); ev1.y = fast_exp2(t1.y);
            e2[2 * k]     = ev0;
            e2[2 * k + 1] = ev1;
            zv0 += ev0;
            zv1 += ev1;
        }
        const v2f zv = zv0 + zv1;
        const float zt = wave_sum_uniform(zv.x + zv.y);    // SGPR-uniform
        const float scale = sdv[ii] * fast_rcp(zt);        // z >= 1
        const v2f sc2 = {scale, scale};
#pragma unroll
        for (int j = 0; j < 8; ++j)
            acc2[j] = e2[j] * sc2 + acc2[j];
    }

    // Stage per-wave accumulators, reduce across the 4 waves in LDS.
#pragma unroll
    for (int k = 0; k < 4; ++k) {
        float4 v;
        v.x = acc2[2 * k].x;     v.y = acc2[2 * k].y;
        v.z = acc2[2 * k + 1].x; v.w = acc2[2 * k + 1].y;
        ((float4*)&red[w][256 * k])[lane] = v;
    }
    __syncthreads();

    const int t = threadIdx.x;
    float4 v = ((const float4*)red[0])[t];
#pragma unroll
    for (int ww = 1; ww < WPB; ++ww) {
        const float4 u = ((const float4*)red[ww])[t];
        v.x += u.x; v.y += u.y; v.z += u.z; v.w += u.w;
    }
    float* ob = out + b * O_ + 4 * t;
    atomicAdd(&ob[0], v.x);
    atomicAdd(&ob[1], v.y);
    atomicAdd(&ob[2], v.z);
    atomicAdd(&ob[3], v.w);
}

// ---------------------------------------------------------------------------
extern "C" void kernel_launch(void* const* d_in, const int* in_sizes, int n_in,
                              void* d_out, int out_size, void* d_ws, size_t ws_size,
                              hipStream_t stream)
{
    const float* data = (const float*)d_in[0];
    const float* ix   = (const float*)d_in[1];
    const float* iy   = (const float*)d_in[2];
    const float* ox   = (const float*)d_in[3];
    const float* oy   = (const float*)d_in[4];
    const float* la   = (const float*)d_in[5];
    const float* lm   = (const float*)d_in[6];
    float* out  = (float*)d_out;
    float* Tt2  = (float*)d_ws;
    unsigned* minbits = (unsigned*)((char*)d_ws + TT_BYTES);

    // init min accumulators to UINT_MAX (tiny; the only extra dispatch)
    (void)hipMemsetAsync(minbits, 0xFF, I_ * sizeof(unsigned), stream);

    build_T2_kernel<<<dim3(I_ / 32, O_ / 32), dim3(32, 8), 0, stream>>>(
        ix, iy, ox, oy, la, lm, Tt2, minbits, out);

    aeg_main_kernel<<<dim3(NCHUNK / WPB, B_), 256, 0, stream>>>(
        data, Tt2, (const float*)minbits, out);
}

// Round 3
// 122.883 us; speedup vs baseline: 1.2621x; 1.2621x over previous
//
#include <hip/hip_runtime.h>

#define B_ 128
#define O_ 1024
#define I_ 1024
#define NCHUNK 64
#define CI (I_ / NCHUNK)     // 16 i-values per wave
#define WPB 4                // waves per block

#define LOG2E_F  1.4426950408889634f
#define LN2_F    0.6931471805599453f
#define LN2SQ_F  0.4804530139182014f          // ln2^2
#define EPSC_F   (1e-7f * LN2SQ_F)            // eps * ln2^2

typedef float v2f __attribute__((ext_vector_type(2)));

__device__ __forceinline__ float fast_rsq(float x)  { return __builtin_amdgcn_rsqf(x); }
__device__ __forceinline__ float fast_exp2(float x) { return __builtin_amdgcn_exp2f(x); }
__device__ __forceinline__ float fast_rcp(float x)  { return __builtin_amdgcn_rcpf(x); }

__device__ __forceinline__ float readlane_f(float x, int l) {
    return __builtin_bit_cast(float,
        __builtin_amdgcn_readlane(__builtin_bit_cast(int, x), l));
}

// DPP combine steps (ctrl must be an immediate -> template param);
// bound_ctrl=true: invalid sources read 0.
template <int CTRL>
__device__ __forceinline__ float dpp_add(float v) {
    int x = __builtin_amdgcn_update_dpp(0, __builtin_bit_cast(int, v),
                                        CTRL, 0xf, 0xf, true);
    return v + __builtin_bit_cast(float, x);
}
template <int CTRL>
__device__ __forceinline__ float dpp_max(float v) {   // valid for v > 0 (id = 0)
    int x = __builtin_amdgcn_update_dpp(0, __builtin_bit_cast(int, v),
                                        CTRL, 0xf, 0xf, true);
    return fmaxf(v, __builtin_bit_cast(float, x));
}
// 64-lane reductions; total lands in lane 63, returned as SGPR-uniform float.
__device__ __forceinline__ float wave_sum_uniform(float v) {
    v = dpp_add<0xB1>(v);   // quad_perm [1,0,3,2] : pair sums
    v = dpp_add<0x4E>(v);   // quad_perm [2,3,0,1] : quad sums
    v = dpp_add<0x141>(v);  // row_half_mirror     : octet sums
    v = dpp_add<0x140>(v);  // row_mirror          : row-of-16 sums
    v = dpp_add<0x142>(v);  // row_bcast15         : rows 1..3 += prev row
    v = dpp_add<0x143>(v);  // row_bcast31         : rows 2,3 += rows 0+1
    return __builtin_bit_cast(float,
        __builtin_amdgcn_readlane(__builtin_bit_cast(int, v), 63));
}
__device__ __forceinline__ float wave_max_uniform(float v) {  // v > 0 required
    v = dpp_max<0xB1>(v);
    v = dpp_max<0x4E>(v);
    v = dpp_max<0x141>(v);
    v = dpp_max<0x140>(v);
    v = dpp_max<0x142>(v);
    v = dpp_max<0x143>(v);
    return __builtin_bit_cast(float,
        __builtin_amdgcn_readlane(__builtin_bit_cast(int, v), 63));
}

// ---------------------------------------------------------------------------
// Fused kernel 1: Tt2[i*O+o] = T[o,i]^2 (transposed+squared), plus zeroing of
// d_out (1024 blocks x 128 elems = 131072 = B*O). No min machinery anymore:
// the softmax max is reduced in-wave inside aeg_main (each column i's 1024
// o-values all live in one wave iteration), which also removed the memset
// dispatch for the min accumulator.
// ---------------------------------------------------------------------------
__global__ __launch_bounds__(256) void build_T2_kernel(
    const float* __restrict__ ix, const float* __restrict__ iy,
    const float* __restrict__ ox, const float* __restrict__ oy,
    const float* __restrict__ la, const float* __restrict__ lm,
    float* __restrict__ Tt2, float* __restrict__ out_zero)
{
    __shared__ float tile[32][33];
    const int i0 = blockIdx.x * 32;
    const int o0 = blockIdx.y * 32;
    const int tx = threadIdx.x;      // 0..31
    const int ty = threadIdx.y;      // 0..7
    const int t  = ty * 32 + tx;     // 0..255

    // fold the d_out zeroing in (saves a memset dispatch)
    const int bid = blockIdx.y * gridDim.x + blockIdx.x;   // 0..1023
    if (t < 128) out_zero[bid * 128 + t] = 0.0f;

#pragma unroll
    for (int r = 0; r < 32; r += 8) {
        const int o = o0 + ty + r;
        const int i = i0 + tx;
        const int idx = o * I_ + i;
        const float tt = fmaf(ix[idx] * fast_rcp(iy[idx]) + la[idx],
                              1.0f + lm[idx],
                              -(ox[idx] * fast_rcp(oy[idx])));
        tile[ty + r][tx] = tt * tt;
    }
    __syncthreads();
#pragma unroll
    for (int r = 0; r < 32; r += 8) {
        Tt2[(i0 + ty + r) * O_ + o0 + tx] = tile[tx][ty + r];
    }
}

// ---------------------------------------------------------------------------
// Kernel 2: wave owns chunk of 16 i's; lane owns 16 o's.
//  - NO min-waves bound: the live set (acc16 + e16 + rows16 + temps) needs
//    ~70 VGPRs; forcing <=64 spills to scratch (measured: 100 MB scratch
//    writes, 2x duration). 7 waves/SIMD is this kernel's ceiling.
//  - Softmax max reduced exactly in-wave per iteration: lane tree-max of its
//    16 t=rsq(q) values (v_max3-friendly) + 6-step DPP-max chain. The next
//    iteration's independent rsq work hides the serial reduce latency.
//  - Prologue lane-parallelized: lane j derives per-i sigmoid values for i=j,
//    then readlane -> SGPR.
// ---------------------------------------------------------------------------
__global__ __launch_bounds__(256) void aeg_main_kernel(
    const float* __restrict__ data,   // (B, I)
    const float* __restrict__ Tt2,    // (I, O) transposed T^2
    float* __restrict__ out)          // (B, O), zeroed by build_T2
{
    __shared__ float red[WPB][O_];    // 16 KB

    const int w    = threadIdx.x >> 6;
    const int lane = threadIdx.x & 63;
    const int chunk = blockIdx.x * WPB + w;
    const int b     = blockIdx.y;

    const float4* rowbase = (const float4*)(Tt2 + (size_t)chunk * CI * O_);

    // ---- prologue: lane j computes per-i derivations for i = chunk*CI + j ----
    const float dv_l  = data[b * I_ + chunk * CI + (lane & 15)];
    const float sig_l = fast_rcp(1.0f + fast_exp2(-dv_l * LOG2E_F));
    const float sc_l  = sig_l * LN2_F;
    const float s2_l  = sc_l * sc_l;

    float sdv[CI], ss2[CI];
#pragma unroll
    for (int j = 0; j < CI; ++j) {
        sdv[j] = readlane_f(dv_l, j);
        ss2[j] = readlane_f(s2_l, j);
    }

    v2f acc2[8];
#pragma unroll
    for (int j = 0; j < 8; ++j) acc2[j] = (v2f)0.0f;

#pragma unroll
    for (int ii = 0; ii < CI; ++ii) {
        const float4* r4 = rowbase + (size_t)ii * (O_ / 4);
        float4 rr[4];
#pragma unroll
        for (int k = 0; k < 4; ++k) rr[k] = r4[lane + 64 * k];

        const v2f s2v = {ss2[ii], ss2[ii]};
        const v2f epv = {EPSC_F, EPSC_F};

        // t = rsq(r*s2 + eps)  (log2-units exponent), kept in t2[8]
        v2f t2[8];
#pragma unroll
        for (int k = 0; k < 4; ++k) {
            const v2f a = {rr[k].x, rr[k].y};
            const v2f c = {rr[k].z, rr[k].w};
            const v2f q0 = a * s2v + epv;
            const v2f q1 = c * s2v + epv;
            v2f t0, t1;
            t0.x = fast_rsq(q0.x); t0.y = fast_rsq(q0.y);
            t1.x = fast_rsq(q1.x); t1.y = fast_rsq(q1.y);
            t2[2 * k]     = t0;
            t2[2 * k + 1] = t1;
        }

        // exact per-column max: lane tree (v_max3-friendly) + DPP chain
        const float h0 = fmaxf(fmaxf(t2[0].x, t2[0].y), fmaxf(t2[1].x, t2[1].y));
        const float h1 = fmaxf(fmaxf(t2[2].x, t2[2].y), fmaxf(t2[3].x, t2[3].y));
        const float h2 = fmaxf(fmaxf(t2[4].x, t2[4].y), fmaxf(t2[5].x, t2[5].y));
        const float h3 = fmaxf(fmaxf(t2[6].x, t2[6].y), fmaxf(t2[7].x, t2[7].y));
        const float m  = wave_max_uniform(fmaxf(fmaxf(h0, h1), fmaxf(h2, h3)));
        const v2f mv = {m, m};

        v2f e2[8];
        v2f zv0 = (v2f)0.0f, zv1 = (v2f)0.0f;
#pragma unroll
        for (int k = 0; k < 4; ++k) {
            const v2f t0 = t2[2 * k]     - mv;
            const v2f t1 = t2[2 * k + 1] - mv;
            v2f ev0, ev1;
            ev0.x = fast_exp2(t0.x); ev0.y = fast_exp2(t0.y);
            ev1.x = fast_exp2(t1.x); ev1.y = fast_exp2(t1.y);
            e2[2 * k]     = ev0;
            e2[2 * k + 1] = ev1;
            zv0 += ev0;
            zv1 += ev1;
        }
        const v2f zv = zv0 + zv1;
        const float zt = wave_sum_uniform(zv.x + zv.y);    // SGPR-uniform
        const float scale = sdv[ii] * fast_rcp(zt);        // z >= 1 (max term = 1)
        const v2f sc2 = {scale, scale};
#pragma unroll
        for (int j = 0; j < 8; ++j)
            acc2[j] = e2[j] * sc2 + acc2[j];
    }

    // Stage per-wave accumulators, reduce across the 4 waves in LDS.
#pragma unroll
    for (int k = 0; k < 4; ++k) {
        float4 v;
        v.x = acc2[2 * k].x;     v.y = acc2[2 * k].y;
        v.z = acc2[2 * k + 1].x; v.w = acc2[2 * k + 1].y;
        ((float4*)&red[w][256 * k])[lane] = v;
    }
    __syncthreads();

    const int t = threadIdx.x;
    float4 v = ((const float4*)red[0])[t];
#pragma unroll
    for (int ww = 1; ww < WPB; ++ww) {
        const float4 u = ((const float4*)red[ww])[t];
        v.x += u.x; v.y += u.y; v.z += u.z; v.w += u.w;
    }
    float* ob = out + b * O_ + 4 * t;
    atomicAdd(&ob[0], v.x);
    atomicAdd(&ob[1], v.y);
    atomicAdd(&ob[2], v.z);
    atomicAdd(&ob[3], v.w);
}

// ---------------------------------------------------------------------------
extern "C" void kernel_launch(void* const* d_in, const int* in_sizes, int n_in,
                              void* d_out, int out_size, void* d_ws, size_t ws_size,
                              hipStream_t stream)
{
    const float* data = (const float*)d_in[0];
    const float* ix   = (const float*)d_in[1];
    const float* iy   = (const float*)d_in[2];
    const float* ox   = (const float*)d_in[3];
    const float* oy   = (const float*)d_in[4];
    const float* la   = (const float*)d_in[5];
    const float* lm   = (const float*)d_in[6];
    float* out  = (float*)d_out;
    float* Tt2  = (float*)d_ws;

    build_T2_kernel<<<dim3(I_ / 32, O_ / 32), dim3(32, 8), 0, stream>>>(
        ix, iy, ox, oy, la, lm, Tt2, out);

    aeg_main_kernel<<<dim3(NCHUNK / WPB, B_), 256, 0, stream>>>(
        data, Tt2, out);
}